// Round 1
// baseline (241.214 us; speedup 1.0000x reference)
//
#include <hip/hip_runtime.h>
#include <stdint.h>

// Problem constants
#define B_SZ 1024
#define Z_SZ 32768
#define D_SZ 128
#define NZ   32                 // z chunks (split-Z)
#define CZ   (Z_SZ / NZ)        // 1024 z per chunk
#define TZ   64                 // z per inner tile
#define ITERS (CZ / TZ)         // 16
#define TBLK 64                 // batch rows per block (4 waves x 16)
#define WROWS 16                // batch rows per wave

// LDS strides (elements). Row byte-strides must be 16B multiples for ds_read_b128.
#define SEMB_STRIDE  136        // 64 x 136 bf16 (row-major emb tile), 272B rows
#define SEMBT_STRIDE 72         // 128 x 72 bf16 (transposed emb tile), 144B rows
#define SP_STRIDE    72         // 16 x 72 bf16 per wave (P tile), 144B rows

// Workspace layout (float offsets)
#define WS_O   0                              // [NZ][B][D]
#define WS_M   (NZ * B_SZ * D_SZ)             // [NZ][B]
#define WS_L   (WS_M + NZ * B_SZ)
#define WS_C   (WS_L + NZ * B_SZ)
#define WS_TAB (WS_C + NZ * B_SZ)             // bf16 tables: embR [Z][D], embT [D][Z]

typedef short bf16x8 __attribute__((ext_vector_type(8)));
typedef float f32x4  __attribute__((ext_vector_type(4)));

#if __has_builtin(__builtin_amdgcn_exp2f)
#define EXP2F(x) __builtin_amdgcn_exp2f(x)
#else
#define EXP2F(x) exp2f(x)
#endif

__device__ __forceinline__ unsigned short f2bf(float f) {
    union { float f; uint32_t u; } v; v.f = f;
    uint32_t u = v.u;
    u = (u + 0x7FFFu + ((u >> 16) & 1u)) >> 16;   // RNE truncate to bf16
    return (unsigned short)u;
}

// ---------------------------------------------------------------------------
// Prep: emb f32 [Z][D] -> bf16 row-major embR [Z][D] and transposed embT [D][Z]
// One block per 64-z tile. Row pass is fully coalesced; transpose goes through
// LDS so global writes are 128B-contiguous per row (8 lanes x 16B per row).
// ---------------------------------------------------------------------------
__global__ __launch_bounds__(256) void prep_tables(
    const float* __restrict__ emb,
    unsigned short* __restrict__ embR,
    unsigned short* __restrict__ embT)
{
    __shared__ __align__(16) unsigned short st[64 * SEMB_STRIDE];
    const int z0 = blockIdx.x * 64;
    const int t  = threadIdx.x;
    {
        const int r = t >> 2, q = t & 3;
        const float* src = emb + (size_t)(z0 + r) * D_SZ + q * 32;
        unsigned short* dR = embR + (size_t)(z0 + r) * D_SZ + q * 32;
        unsigned short* dL = st + r * SEMB_STRIDE + q * 32;
#pragma unroll
        for (int u = 0; u < 8; ++u) {
            float4 x = *(const float4*)(src + 4 * u);
            ushort4 h;
            h.x = f2bf(x.x); h.y = f2bf(x.y); h.z = f2bf(x.z); h.w = f2bf(x.w);
            *(ushort4*)(dR + 4 * u) = h;
            *(ushort4*)(dL + 4 * u) = h;
        }
    }
    __syncthreads();
    {
        const int lane = t & 63, w = t >> 6;
#pragma unroll
        for (int i = 0; i < 4; ++i) {
            const int d = w * 32 + i * 8 + (lane >> 3);   // 0..127
            const int c = lane & 7;                       // 8-z chunk
            bf16x8 v;
#pragma unroll
            for (int k = 0; k < 8; ++k) v[k] = (short)st[(c * 8 + k) * SEMB_STRIDE + d];
            *(bf16x8*)(embT + (size_t)d * Z_SZ + z0 + c * 8) = v;
        }
    }
}

__global__ __launch_bounds__(256, 2) void attn_part(
    const int*            __restrict__ zs,
    const float*          __restrict__ ctx,
    const unsigned short* __restrict__ embR,
    const unsigned short* __restrict__ embT,
    float*                __restrict__ ws)
{
    __shared__ __align__(16) unsigned short s_emb [TZ   * SEMB_STRIDE];   // 17408 B
    __shared__ __align__(16) unsigned short s_embT[D_SZ * SEMBT_STRIDE];  // 18432 B
    __shared__ __align__(16) unsigned short s_P   [4 * WROWS * SP_STRIDE];// 9216 B

    const int tid  = threadIdx.x;
    const int wave = tid >> 6;
    const int lane = tid & 63;
    const int l15  = lane & 15;
    const int quad = lane >> 4;

    const int bg     = blockIdx.x;            // 0..15 batch group
    const int ch     = blockIdx.y;            // 0..31 z-chunk
    const int z_base = ch * CZ;
    const int wb0    = bg * TBLK + wave * WROWS;  // first batch row of this wave

    // staging thread mappings (fixed for the whole kernel)
    const int srow = tid >> 2, sq3 = tid & 3;   // row tile: 64B per thread
    const int sd   = tid >> 1, sh  = tid & 1;   // transposed tile: 64B per thread

    // ---- ctx A-fragments, scaled by log2(e)/sqrt(D) (base-2 softmax), in regs ----
    bf16x8 afrag[4];
    {
        const float scale = (float)(1.4426950408889634 * 0.08838834764831845);
        const float* crow = ctx + (size_t)(wb0 + l15) * D_SZ;
#pragma unroll
        for (int ks = 0; ks < 4; ++ks) {
            const float* p = crow + ks * 32 + quad * 8;
            float4 x0 = *(const float4*)(p);
            float4 x1 = *(const float4*)(p + 4);
            bf16x8 a;
            a[0] = (short)f2bf(x0.x * scale); a[1] = (short)f2bf(x0.y * scale);
            a[2] = (short)f2bf(x0.z * scale); a[3] = (short)f2bf(x0.w * scale);
            a[4] = (short)f2bf(x1.x * scale); a[5] = (short)f2bf(x1.y * scale);
            a[6] = (short)f2bf(x1.z * scale); a[7] = (short)f2bf(x1.w * scale);
            afrag[ks] = a;
        }
    }

    // ---- online-softmax state (base-2), per reg-row r: row b = wb0 + quad*4 + r ----
    float m_r[4], l_r[4];
    int   cnt_r[4];
    f32x4 acc2[8];
#pragma unroll
    for (int r = 0; r < 4; ++r) { m_r[r] = -1e30f; l_r[r] = 0.f; cnt_r[r] = 0; }
#pragma unroll
    for (int n = 0; n < 8; ++n) { acc2[n][0]=0.f; acc2[n][1]=0.f; acc2[n][2]=0.f; acc2[n][3]=0.f; }

    // ---- T14 async-STAGE registers: tile data + mask dwords for the NEXT tile ----
    bf16x8 rA[4], rT[4];
    int mi[4][4];

    // preload tile 0
    {
        const unsigned short* srcR = embR + (size_t)(z_base + srow) * D_SZ + sq3 * 32;
        const unsigned short* srcT = embT + (size_t)sd * Z_SZ + z_base + sh * 32;
#pragma unroll
        for (int u = 0; u < 4; ++u) {
            rA[u] = *(const bf16x8*)(srcR + u * 8);
            rT[u] = *(const bf16x8*)(srcT + u * 8);
        }
#pragma unroll
        for (int r = 0; r < 4; ++r) {
            const int b = wb0 + quad * 4 + r;
            const int* p = zs + (size_t)b * Z_SZ + z_base + l15;
#pragma unroll
            for (int nt = 0; nt < 4; ++nt) mi[nt][r] = p[nt * 16];
        }
    }

    for (int it = 0; it < ITERS; ++it) {
        __syncthreads();   // previous tile's LDS reads complete

        // ---- write staged registers to LDS (no conversion work) ----
        {
            unsigned short* dst = s_emb + srow * SEMB_STRIDE + sq3 * 32;
#pragma unroll
            for (int u = 0; u < 4; ++u) *(bf16x8*)(dst + u * 8) = rA[u];
        }
        {
            unsigned short* dst = s_embT + sd * SEMBT_STRIDE + sh * 32;
#pragma unroll
            for (int u = 0; u < 4; ++u) *(bf16x8*)(dst + u * 8) = rT[u];
        }

        // ---- mask bits for current tile (from prefetched dwords) ----
        int msk[4][4];
#pragma unroll
        for (int r = 0; r < 4; ++r) {
#pragma unroll
            for (int nt = 0; nt < 4; ++nt) msk[nt][r] = (mi[nt][r] > 0) ? 1 : 0;
            cnt_r[r] += msk[0][r] + msk[1][r] + msk[2][r] + msk[3][r];
        }

        __syncthreads();   // staging visible

        // ---- issue next tile's global loads; latency hides under the MFMA work ----
        if (it + 1 < ITERS) {
            const int z0n = z_base + (it + 1) * TZ;
            const unsigned short* srcR = embR + (size_t)(z0n + srow) * D_SZ + sq3 * 32;
            const unsigned short* srcT = embT + (size_t)sd * Z_SZ + z0n + sh * 32;
#pragma unroll
            for (int u = 0; u < 4; ++u) {
                rA[u] = *(const bf16x8*)(srcR + u * 8);
                rT[u] = *(const bf16x8*)(srcT + u * 8);
            }
#pragma unroll
            for (int r = 0; r < 4; ++r) {
                const int b = wb0 + quad * 4 + r;
                const int* p = zs + (size_t)b * Z_SZ + z0n + l15;
#pragma unroll
                for (int nt = 0; nt < 4; ++nt) mi[nt][r] = p[nt * 16];
            }
        }

        // ---- GEMM1: S[16 x 64] = ctx_tile @ emb_tile^T (K = 128), base-2 scaled ----
        f32x4 sfr[4];
#pragma unroll
        for (int nt = 0; nt < 4; ++nt) {
            f32x4 c; c[0]=0.f; c[1]=0.f; c[2]=0.f; c[3]=0.f;
            const unsigned short* bb = s_emb + (nt * 16 + l15) * SEMB_STRIDE + quad * 8;
#pragma unroll
            for (int ks = 0; ks < 4; ++ks) {
                bf16x8 bf = *(const bf16x8*)(bb + ks * 32);
                c = __builtin_amdgcn_mfma_f32_16x16x32_bf16(afrag[ks], bf, c, 0, 0, 0);
            }
            sfr[nt] = c;
        }

        // ---- masked online softmax (base-2; rows replicated across 16 lanes of a quad) ----
        float tmax[4];
#pragma unroll
        for (int r = 0; r < 4; ++r) {
            float a0 = msk[0][r] ? sfr[0][r] : -1e30f;
            float a1 = msk[1][r] ? sfr[1][r] : -1e30f;
            float a2 = msk[2][r] ? sfr[2][r] : -1e30f;
            float a3 = msk[3][r] ? sfr[3][r] : -1e30f;
            tmax[r] = fmaxf(fmaxf(a0, a1), fmaxf(a2, a3));
        }
#pragma unroll
        for (int s = 1; s < 16; s <<= 1) {
#pragma unroll
            for (int r = 0; r < 4; ++r) tmax[r] = fmaxf(tmax[r], __shfl_xor(tmax[r], s));
        }
        float alpha[4];
#pragma unroll
        for (int r = 0; r < 4; ++r) {
            float mnew = fmaxf(m_r[r], tmax[r]);
            alpha[r] = EXP2F(m_r[r] - mnew);    // m=-1e30 twice -> 2^0=1, l stays 0
            m_r[r] = mnew;
            l_r[r] *= alpha[r];
        }
        // p = mask ? 2^(s - m) : 0 ; write P to per-wave LDS (A-operand layout route)
        float psum[4]; psum[0]=0.f; psum[1]=0.f; psum[2]=0.f; psum[3]=0.f;
        unsigned short* pw = s_P + wave * (WROWS * SP_STRIDE);
#pragma unroll
        for (int nt = 0; nt < 4; ++nt) {
#pragma unroll
            for (int r = 0; r < 4; ++r) {
                float p = msk[nt][r] ? EXP2F(sfr[nt][r] - m_r[r]) : 0.f;
                psum[r] += p;
                pw[(quad * 4 + r) * SP_STRIDE + nt * 16 + l15] = f2bf(p);
            }
        }
#pragma unroll
        for (int s = 1; s < 16; s <<= 1) {
#pragma unroll
            for (int r = 0; r < 4; ++r) psum[r] += __shfl_xor(psum[r], s);
        }
#pragma unroll
        for (int r = 0; r < 4; ++r) l_r[r] += psum[r];

        // rescale O accumulator by alpha (alpha[r] replicated across quad lanes)
#pragma unroll
        for (int n = 0; n < 8; ++n) {
#pragma unroll
            for (int r = 0; r < 4; ++r) acc2[n][r] *= alpha[r];
        }

        // ---- GEMM2: O[16 x 128] += P[16 x 64] @ emb_tile[64 x 128] (K = 64) ----
        const unsigned short* pb = pw + l15 * SP_STRIDE + quad * 8;
        bf16x8 pA0 = *(const bf16x8*)(pb);
        bf16x8 pA1 = *(const bf16x8*)(pb + 32);
#pragma unroll
        for (int nt2 = 0; nt2 < 8; ++nt2) {
            const unsigned short* tb = s_embT + (nt2 * 16 + l15) * SEMBT_STRIDE + quad * 8;
            bf16x8 b0 = *(const bf16x8*)(tb);
            bf16x8 b1 = *(const bf16x8*)(tb + 32);
            acc2[nt2] = __builtin_amdgcn_mfma_f32_16x16x32_bf16(pA0, b0, acc2[nt2], 0, 0, 0);
            acc2[nt2] = __builtin_amdgcn_mfma_f32_16x16x32_bf16(pA1, b1, acc2[nt2], 0, 0, 0);
        }
    }

    // ---- epilogue: partial O, m, l, count to workspace ----
#pragma unroll
    for (int nt2 = 0; nt2 < 8; ++nt2) {
#pragma unroll
        for (int r = 0; r < 4; ++r) {
            const int b = wb0 + quad * 4 + r;
            ws[WS_O + ((size_t)ch * B_SZ + b) * D_SZ + nt2 * 16 + l15] = acc2[nt2][r];
        }
    }
    float cntf[4];
#pragma unroll
    for (int r = 0; r < 4; ++r) cntf[r] = (float)cnt_r[r];
#pragma unroll
    for (int s = 1; s < 16; s <<= 1) {
#pragma unroll
        for (int r = 0; r < 4; ++r) cntf[r] += __shfl_xor(cntf[r], s);
    }
    if (l15 == 0) {
#pragma unroll
        for (int r = 0; r < 4; ++r) {
            const int b = wb0 + quad * 4 + r;
            ws[WS_M + ch * B_SZ + b] = m_r[r];
            ws[WS_L + ch * B_SZ + b] = l_r[r];
            ws[WS_C + ch * B_SZ + b] = cntf[r];
        }
    }
}

__global__ __launch_bounds__(128) void attn_reduce(
    const float* __restrict__ ws, float* __restrict__ out)
{
    const int b = blockIdx.x;
    const int d = threadIdx.x;
    const float* mP = ws + WS_M;
    const float* lP = ws + WS_L;
    const float* cP = ws + WS_C;

    float M = -1e30f;
#pragma unroll
    for (int c = 0; c < NZ; ++c) M = fmaxf(M, mP[c * B_SZ + b]);

    float L = 0.f, C = 0.f, acc = 0.f;
#pragma unroll
    for (int c = 0; c < NZ; ++c) {
        float w = EXP2F(mP[c * B_SZ + b] - M);
        L += lP[c * B_SZ + b] * w;
        C += cP[c * B_SZ + b];
        acc += ws[WS_O + ((size_t)c * B_SZ + b) * D_SZ + d] * w;
    }
    float cnt = fmaxf(C, 1.0f);
    out[(size_t)b * D_SZ + d] = (L > 0.f) ? acc / (L * cnt) : 0.f;
}

extern "C" void kernel_launch(void* const* d_in, const int* in_sizes, int n_in,
                              void* d_out, int out_size, void* d_ws, size_t ws_size,
                              hipStream_t stream) {
    (void)in_sizes; (void)n_in; (void)out_size; (void)ws_size;
    const int*   zs  = (const int*)  d_in[0];
    const float* ctx = (const float*)d_in[1];
    const float* emb = (const float*)d_in[2];
    float* out = (float*)d_out;
    float* ws  = (float*)d_ws;

    unsigned short* embR = (unsigned short*)(ws + WS_TAB);
    unsigned short* embT = embR + (size_t)Z_SZ * D_SZ;

    prep_tables<<<Z_SZ / 64, 256, 0, stream>>>(emb, embR, embT);

    dim3 grid1(B_SZ / TBLK, NZ);   // (16, 32): consecutive blocks share a z-chunk -> L2 reuse of emb
    attn_part<<<grid1, 256, 0, stream>>>(zs, ctx, embR, embT, ws);
    attn_reduce<<<B_SZ, 128, 0, stream>>>(ws, out);
}